// Round 1
// baseline (15781.158 us; speedup 1.0000x reference)
//
#include <hip/hip_runtime.h>

typedef _Float16 half_t;
typedef half_t f16x8 __attribute__((ext_vector_type(8)));
typedef float  f32x4 __attribute__((ext_vector_type(4)));
typedef unsigned int u32;

#define T_STEPS 256
#define IN0     64
#define HID     256
#define BM      16
#define KC0     10   // (64+256)/32
#define KC1     16   // (256+256)/32

#define B0_HALVES (8*8*KC0*512)   // 327680 halves
#define B1_HALVES (8*8*KC1*512)   // 524288 halves
// ws: [B0 | B1] fp16 packed B-fragments, 1,703,936 bytes total

// ---------------- prep: pack fp32 weights into fp16 MFMA B-fragment order ----------------
// Layout: [wave][jtile 8][kchunk][lane 64][8 halves]; jtile j -> gate g=j>>1, half16 = j&1
// B[k][col] = W_cat[col][k];  col = g*256 + wave*32 + (j&1)*16 + (lane&15);
// k = kc*32 + (lane>>4)*8 + j8   (A/B frag: 4 lane-groups of 16, 8 contiguous k per lane)
__global__ void pack_weights(const float* __restrict__ wih0, const float* __restrict__ whh0,
                             const float* __restrict__ wih1, const float* __restrict__ whh1,
                             half_t* __restrict__ wsB) {
  int idx = blockIdx.x * 256 + threadIdx.x;
  if (idx < B0_HALVES) {
    int w = idx / 40960;          // 8*KC0*512
    int r = idx % 40960;
    int j = r / 5120;             // KC0*512
    int r2 = r % 5120;
    int kc = r2 / 512;
    int lid = r2 % 512;
    int lane = lid >> 3, j8 = lid & 7;
    int col = (j >> 1) * 256 + w * 32 + (j & 1) * 16 + (lane & 15);
    int k = kc * 32 + (lane >> 4) * 8 + j8;
    float v = (k < IN0) ? wih0[col * IN0 + k] : whh0[col * HID + (k - IN0)];
    wsB[idx] = (half_t)v;
  } else {
    int i1 = idx - B0_HALVES;
    int w = i1 / 65536;           // 8*KC1*512
    int r = i1 % 65536;
    int j = r / 8192;             // KC1*512
    int r2 = r % 8192;
    int kc = r2 / 512;
    int lid = r2 % 512;
    int lane = lid >> 3, j8 = lid & 7;
    int col = (j >> 1) * 256 + w * 32 + (j & 1) * 16 + (lane & 15);
    int k = kc * 32 + (lane >> 4) * 8 + j8;
    float v = (k < HID) ? wih1[col * HID + k] : whh1[col * HID + (k - HID)];
    wsB[idx] = (half_t)v;
  }
}

__device__ __forceinline__ float sigm(float x)   { return 1.0f / (1.0f + __expf(-x)); }
__device__ __forceinline__ float tanh_f(float x) { return 1.0f - 2.0f / (__expf(2.0f * x) + 1.0f); }
__device__ __forceinline__ float wsum(float v) {
  #pragma unroll
  for (int m = 1; m < 64; m <<= 1) v += __shfl_xor(v, m, 64);
  return v;
}
__device__ __forceinline__ f16x8 as_f16x8(uint4 v) {
  union { uint4 u; f16x8 h; } c; c.u = v; return c.h;
}

// One K-panel of the gate matmul: 8 N-tiles x CNT K-chunks.
// A from swizzled LDS (byte ^= (row&7)<<4 -> conflict-free b128 reads),
// B streamed from L2 in prepacked fragment order (coalesced dwordx4), 6-deep prefetch ring.
template<int CNT>
__device__ __forceinline__ void mm_phase(f32x4 (&acc)[8], const char* Abase, int strideB,
                                         const uint4* __restrict__ Bw, int KCS, int kcBase,
                                         int l15, int l4) {
  f16x8 a[CNT];
  #pragma unroll
  for (int kc = 0; kc < CNT; kc++) {
    int byo = l15 * strideB + (kcBase + kc) * 64 + l4 * 16;
    byo ^= (l15 & 7) << 4;
    a[kc] = *(const f16x8*)(Abase + byo);
  }
  const int N = 8 * CNT;
  uint4 b[8];
  #pragma unroll
  for (int i = 0; i < 6; i++)
    b[i] = Bw[((i / CNT) * KCS + kcBase + (i % CNT)) * 64];
  #pragma unroll
  for (int idx = 0; idx < N; idx++) {
    int pf = idx + 6;
    if (pf < N) b[pf & 7] = Bw[((pf / CNT) * KCS + kcBase + (pf % CNT)) * 64];
    acc[idx / CNT] = __builtin_amdgcn_mfma_f32_16x16x32_f16(
        a[idx % CNT], as_f16x8(b[idx & 7]), acc[idx / CNT], 0, 0, 0);
  }
}

// 32 blocks x 512 threads (8 waves). Block owns 16 batch rows; wave owns 32 hidden units
// (all four gates for them) -> cell update is lane-local on C-fragments; h exchanged via LDS.
__global__ __launch_bounds__(512, 2)
void lstm_fused(const float* __restrict__ x,
                const float* __restrict__ bih0, const float* __restrict__ bhh0,
                const float* __restrict__ bih1, const float* __restrict__ bhh1,
                const float* __restrict__ gam, const float* __restrict__ bet,
                const float* __restrict__ headw, const float* __restrict__ headb,
                const half_t* __restrict__ wsB,
                float* __restrict__ out) {
  __shared__ __align__(16) char smem[43008];
  char* A0 = smem;                    // [16 rows][320 k] f16, stride 640 B  (x_t | hA)
  char* A1 = smem + 10240;            // [16 rows][512 k] f16, stride 1024 B (hA | hB)
  float* H2 = (float*)(smem + 26624); // [16][256] f32 final h2

  const int tid = threadIdx.x;
  const int w = tid >> 6, lane = tid & 63;
  const int l15 = lane & 15, l4 = lane >> 4;
  const int br0 = blockIdx.x * BM;

  // per-tile bias (col-dependent only): b_ih + b_hh
  float bv0[8], bv1[8];
  #pragma unroll
  for (int j = 0; j < 8; j++) {
    int col = (j >> 1) * 256 + w * 32 + (j & 1) * 16 + l15;
    bv0[j] = bih0[col] + bhh0[col];
    bv1[j] = bih1[col] + bhh1[col];
  }

  const uint4* Bw0 = (const uint4*)wsB + w * (8 * KC0 * 64) + lane;
  const uint4* Bw1 = (const uint4*)(wsB + B0_HALVES) + w * (8 * KC1 * 64) + lane;

  // zero A0+A1 (h0 = 0)
  for (int i = tid; i < 26624 / 4; i += 512) ((u32*)smem)[i] = 0;

  { // stage x_0 into A0 k=[0,64)
    int r = tid >> 5, k = (tid & 31) * 2;
    float2 v = *(const float2*)(x + ((size_t)(br0 + r) * T_STEPS + 0) * IN0 + k);
    union { half_t h[2]; u32 u; } cv;
    cv.h[0] = (half_t)v.x; cv.h[1] = (half_t)v.y;
    int byo = r * 640 + k * 2; byo ^= (r & 7) << 4;
    *(u32*)(A0 + byo) = cv.u;
  }
  __syncthreads();

  float cA[8], cB[8];
  #pragma unroll
  for (int i = 0; i < 8; i++) { cA[i] = 0.f; cB[i] = 0.f; }

  for (int t = 0; t < T_STEPS; t++) {
    // ---------- layer 0: gates = [x_t | hA] @ Wcat0^T ----------
    f32x4 accA[8] = {};
    mm_phase<KC0>(accA, A0, 640, Bw0, KC0, 0, l15, l4);
    float hA[8];
    #pragma unroll
    for (int h16 = 0; h16 < 2; h16++)
      #pragma unroll
      for (int r = 0; r < 4; r++) {
        float xi = accA[0 + h16][r] + bv0[0 + h16];
        float xf = accA[2 + h16][r] + bv0[2 + h16];
        float xg = accA[4 + h16][r] + bv0[4 + h16];
        float xo = accA[6 + h16][r] + bv0[6 + h16];
        int ci = h16 * 4 + r;
        float c = sigm(xf) * cA[ci] + sigm(xi) * tanh_f(xg);
        cA[ci] = c;
        hA[ci] = sigm(xo) * tanh_f(c);
      }
    __syncthreads();  // b1: all waves done reading A0/A1

    #pragma unroll
    for (int h16 = 0; h16 < 2; h16++)
      #pragma unroll
      for (int r = 0; r < 4; r++) {
        int brow = l4 * 4 + r;                    // C/D layout row
        int unit = w * 32 + h16 * 16 + l15;       // C/D layout col
        half_t hv = (half_t)hA[h16 * 4 + r];
        int b0 = brow * 640 + (IN0 + unit) * 2;  b0 ^= (brow & 7) << 4;
        *(half_t*)(A0 + b0) = hv;                 // hA -> layer0 recurrent input
        int b1o = brow * 1024 + unit * 2;        b1o ^= (brow & 7) << 4;
        *(half_t*)(A1 + b1o) = hv;                // hA -> layer1 input
      }
    if (t + 1 < T_STEPS) { // stage x_{t+1}
      int r = tid >> 5, k = (tid & 31) * 2;
      float2 v = *(const float2*)(x + ((size_t)(br0 + r) * T_STEPS + (t + 1)) * IN0 + k);
      union { half_t h[2]; u32 u; } cv;
      cv.h[0] = (half_t)v.x; cv.h[1] = (half_t)v.y;
      int byo = r * 640 + k * 2; byo ^= (r & 7) << 4;
      *(u32*)(A0 + byo) = cv.u;
    }
    __syncthreads();  // b2: hA + x staged

    // ---------- layer 1: gates = [hA | hB] @ Wcat1^T ----------
    f32x4 accB[8] = {};
    mm_phase<8>(accB, A1, 1024, Bw1, KC1, 0, l15, l4);
    mm_phase<8>(accB, A1, 1024, Bw1, KC1, 8, l15, l4);
    float hB[8];
    #pragma unroll
    for (int h16 = 0; h16 < 2; h16++)
      #pragma unroll
      for (int r = 0; r < 4; r++) {
        float xi = accB[0 + h16][r] + bv1[0 + h16];
        float xf = accB[2 + h16][r] + bv1[2 + h16];
        float xg = accB[4 + h16][r] + bv1[4 + h16];
        float xo = accB[6 + h16][r] + bv1[6 + h16];
        int ci = h16 * 4 + r;
        float c = sigm(xf) * cB[ci] + sigm(xi) * tanh_f(xg);
        cB[ci] = c;
        hB[ci] = sigm(xo) * tanh_f(c);
      }
    __syncthreads();  // b3: all waves done reading A1

    #pragma unroll
    for (int h16 = 0; h16 < 2; h16++)
      #pragma unroll
      for (int r = 0; r < 4; r++) {
        int brow = l4 * 4 + r;
        int unit = w * 32 + h16 * 16 + l15;
        int bb = brow * 1024 + (HID + unit) * 2; bb ^= (brow & 7) << 4;
        *(half_t*)(A1 + bb) = (half_t)hB[h16 * 4 + r];
        if (t == T_STEPS - 1) H2[brow * 256 + unit] = hB[h16 * 4 + r];
      }
  }
  __syncthreads();

  // ---------- LayerNorm + exact GELU + head on h2[:, -1] ----------
  float hbv = headb[0];
  for (int rj = 0; rj < 2; rj++) {
    int rr = w * 2 + rj;
    float v[4], s = 0.f;
    #pragma unroll
    for (int q = 0; q < 4; q++) { v[q] = H2[rr * 256 + q * 64 + lane]; s += v[q]; }
    s = wsum(s);
    float mu = s * (1.0f / 256.0f);
    float vs = 0.f;
    #pragma unroll
    for (int q = 0; q < 4; q++) { float d = v[q] - mu; vs += d * d; }
    vs = wsum(vs);
    float rstd = rsqrtf(vs * (1.0f / 256.0f) + 1e-5f);
    float dot = 0.f;
    #pragma unroll
    for (int q = 0; q < 4; q++) {
      int uu = q * 64 + lane;
      float y = (v[q] - mu) * rstd * gam[uu] + bet[uu];
      float ge = 0.5f * y * (1.0f + erff(y * 0.70710678118f));
      dot += ge * headw[uu];
    }
    dot = wsum(dot);
    if (lane == 0) out[br0 + rr] = dot + hbv;
  }
}

extern "C" void kernel_launch(void* const* d_in, const int* in_sizes, int n_in,
                              void* d_out, int out_size, void* d_ws, size_t ws_size,
                              hipStream_t stream) {
  const float* x    = (const float*)d_in[0];
  const float* wih0 = (const float*)d_in[1];
  const float* whh0 = (const float*)d_in[2];
  const float* bih0 = (const float*)d_in[3];
  const float* bhh0 = (const float*)d_in[4];
  const float* wih1 = (const float*)d_in[5];
  const float* whh1 = (const float*)d_in[6];
  const float* bih1 = (const float*)d_in[7];
  const float* bhh1 = (const float*)d_in[8];
  const float* gam  = (const float*)d_in[9];
  const float* bet  = (const float*)d_in[10];
  const float* hw   = (const float*)d_in[11];
  const float* hb   = (const float*)d_in[12];
  half_t* wsB = (half_t*)d_ws;  // needs 1,703,936 bytes

  hipLaunchKernelGGL(pack_weights, dim3((B0_HALVES + B1_HALVES) / 256), dim3(256), 0, stream,
                     wih0, whh0, wih1, whh1, wsB);
  hipLaunchKernelGGL(lstm_fused, dim3(32), dim3(512), 0, stream,
                     x, bih0, bhh0, bih1, bhh1, gam, bet, hw, hb, wsB, (float*)d_out);
}

// Round 2
// 3420.882 us; speedup vs baseline: 4.6132x; 4.6132x over previous
//
#include <hip/hip_runtime.h>

typedef _Float16 half_t;
typedef half_t f16x8 __attribute__((ext_vector_type(8)));
typedef float  f32x4 __attribute__((ext_vector_type(4)));
typedef unsigned int u32;

#define T_STEPS 256
#define NBG 32
#define NHG 8

// workspace layout (bytes)
#define WB_BYTES  1703936u                  // packed fp16 weight B-fragments
#define G1_OFF    WB_BYTES                  // [2][512][256] half  (h1, by step parity)
#define G2_OFF    (G1_OFF + 524288u)        // [2][512][256] half  (h2)
#define G2F_OFF   (G2_OFF + 524288u)        // [512][256] float    (final h2, f32)
#define FL_OFF    (G2F_OFF + 524288u)       // (T_STEPS+1)*NBG u32 flags
#define NFLAGS    ((T_STEPS + 1) * NBG)

__global__ void init_flags(u32* __restrict__ f) {
  int i = blockIdx.x * 512 + threadIdx.x;
  if (i < NFLAGS) f[i] = 0u;
}

// Pack fp32 weights into fp16 MFMA B-fragment order.
// Layout: [hg 8][w 8][kc 26][lane 64][8 halves]; kc 0..9 = layer0 (K=320), 10..25 = layer1 (K=512).
// Wave (hg,w) owns 16 gate-cols: col16 c -> gate g=c>>2, unit = hg*32 + w*4 + (c&3).
// B[k][col16=lane&15], k = kc*32 + (lane>>4)*8 + j  (16x16x32 f16 A/B fragment mapping).
__global__ void pack_weights(const float* __restrict__ wih0, const float* __restrict__ whh0,
                             const float* __restrict__ wih1, const float* __restrict__ whh1,
                             half_t* __restrict__ wsB) {
  int idx = blockIdx.x * 256 + threadIdx.x;       // < 64*26*512 = 851968
  int j    = idx & 7;
  int lane = (idx >> 3) & 63;
  int kc   = (idx >> 9) % 26;
  int sl   = (idx >> 9) / 26;                     // hg*8 + w
  int hg = sl >> 3, w = sl & 7;
  int c16 = lane & 15;
  int g = c16 >> 2, ul = c16 & 3;
  int col = g * 256 + hg * 32 + w * 4 + ul;       // row in [4H, K] weight (PyTorch i,f,g,o)
  int kf = ((lane >> 4) << 3) + j;
  float v;
  if (kc < 10) { int kk = kc * 32 + kf;        v = (kk < 64)  ? wih0[col * 64 + kk]  : whh0[col * 256 + kk - 64]; }
  else         { int kk = (kc - 10) * 32 + kf; v = (kk < 256) ? wih1[col * 256 + kk] : whh1[col * 256 + kk - 256]; }
  wsB[idx] = (half_t)v;
}

__device__ __forceinline__ float sigm(float x)   { return 1.0f / (1.0f + __expf(-x)); }
__device__ __forceinline__ float tanh_f(float x) { return 1.0f - 2.0f / (__expf(2.0f * x) + 1.0f); }
__device__ __forceinline__ float wsum(float v) {
  #pragma unroll
  for (int m = 1; m < 64; m <<= 1) v += __shfl_xor(v, m, 64);
  return v;
}

// LDS map (45312 B):
//   XH[2]  : [16][64]  f16, row stride 128B, off 0 / 2048        (x_t, x_{t+1})
//   H1[2]  : [16][256] f16, row stride 512B, off 4096 / 12288    (h1 by parity)
//   H2[2]  : [16][256] f16, row stride 512B, off 20480 / 28672   (h2 by parity)
//   gbuf   : [4][16][33] f32, off 36864 (8448B)  -- conflict-free acc exchange
// All f16 tiles XOR-swizzled: byte ^= (row&7)<<4 (G4: breaks the stride-512 32-way conflict).
__global__ __launch_bounds__(512, 2)
void lstm_fused(const float* __restrict__ x,
                const float* __restrict__ bih0, const float* __restrict__ bhh0,
                const float* __restrict__ bih1, const float* __restrict__ bhh1,
                const float* __restrict__ gam, const float* __restrict__ bet,
                const float* __restrict__ headw, const float* __restrict__ headb,
                char* __restrict__ ws, float* __restrict__ out) {
  __shared__ __align__(16) char smem[45312];
  float* gbuf = (float*)(smem + 36864);

  const int tid = threadIdx.x;
  const int w = tid >> 6, lane = tid & 63;
  const int l15 = lane & 15, l4 = lane >> 4;
  const int hg = blockIdx.x >> 5, bg = blockIdx.x & 31;  // partners of a bg share bid%8 -> same XCD
  const int crow = tid >> 5, cu = tid & 31;              // cell-update ownership: 16x32 = 512

  half_t* wsB = (half_t*)ws;
  half_t* G1  = (half_t*)(ws + G1_OFF);
  half_t* G2  = (half_t*)(ws + G2_OFF);
  float*  G2F = (float*)(ws + G2F_OFF);
  u32*    FL  = (u32*)(ws + FL_OFF);

  // ---- weights -> VGPRs, once (104 VGPRs/lane) ----
  f16x8 B0r[10], B1r[16];
  { const f16x8* wp = (const f16x8*)wsB + (hg * 8 + w) * 26 * 64 + lane;
    #pragma unroll
    for (int kc = 0; kc < 10; kc++) B0r[kc] = wp[kc * 64];
    #pragma unroll
    for (int kc = 0; kc < 16; kc++) B1r[kc] = wp[(10 + kc) * 64];
  }

  float bv0[4], bv1[4];
  #pragma unroll
  for (int g = 0; g < 4; g++) {
    int c = g * 256 + hg * 32 + cu;
    bv0[g] = bih0[c] + bhh0[c];
    bv1[g] = bih1[c] + bhh1[c];
  }
  float c0 = 0.f, c1 = 0.f;

  // zero H1[1], H2[1] (h[-1]=0); stage x_0 into XH[0]
  { u32* z1 = (u32*)(smem + 12288);
    u32* z2 = (u32*)(smem + 28672);
    for (int i = tid; i < 2048; i += 512) { z1[i] = 0u; z2[i] = 0u; }
    float2 v0 = *(const float2*)(x + ((bg * 16 + crow) * T_STEPS + 0) * 64 + (tid & 31) * 2);
    union { half_t h[2]; u32 u; } cvx;
    cvx.h[0] = (half_t)v0.x; cvx.h[1] = (half_t)v0.y;
    int bx = crow * 128 + (tid & 31) * 4; bx ^= (crow & 7) << 4;
    *(u32*)(smem + bx) = cvx.u;
  }
  __syncthreads();

  for (int t = 0; t < T_STEPS; t++) {
    const int pc = t & 1, pm = pc ^ 1;
    char* XHc = smem + pc * 2048;
    char* H1p = smem + 4096  + pm * 8192;  // h1[t-1]
    char* H1c = smem + 4096  + pc * 8192;  // h1[t] (staged mid-step)
    char* H2p = smem + 20480 + pm * 8192;  // h2[t-1]

    // issue x_{t+1} load early (hides under MM0)
    float2 xv;
    const bool have_x = (t + 1 < T_STEPS);
    if (have_x) xv = *(const float2*)(x + ((bg * 16 + crow) * T_STEPS + (t + 1)) * 64 + (tid & 31) * 2);

    // ---- layer 0: gates = [x_t | h1[t-1]] @ W0^T, B from regs ----
    f32x4 acc = {0.f, 0.f, 0.f, 0.f};
    #pragma unroll
    for (int kc = 0; kc < 10; kc++) {
      const char* bsrc; int byo;
      if (kc < 2) { bsrc = XHc; byo = l15 * 128 + kc * 64 + l4 * 16; }
      else        { bsrc = H1p; byo = l15 * 512 + (kc - 2) * 64 + l4 * 16; }
      byo ^= (l15 & 7) << 4;
      f16x8 a = *(const f16x8*)(bsrc + byo);
      acc = __builtin_amdgcn_mfma_f32_16x16x32_f16(a, B0r[kc], acc, 0, 0, 0);
    }
    { int g = l15 >> 2, uc = (w << 2) + (l15 & 3);
      #pragma unroll
      for (int r = 0; r < 4; r++) gbuf[g * 528 + (l4 * 4 + r) * 33 + uc] = acc[r]; }
    __syncthreads();

    // ---- cell 0 (one cell/thread, c0 in reg), h1 -> global slice ----
    { float gi = gbuf[0 * 528 + crow * 33 + cu] + bv0[0];
      float gf = gbuf[1 * 528 + crow * 33 + cu] + bv0[1];
      float gg = gbuf[2 * 528 + crow * 33 + cu] + bv0[2];
      float go = gbuf[3 * 528 + crow * 33 + cu] + bv0[3];
      c0 = sigm(gf) * c0 + sigm(gi) * tanh_f(gg);
      float h = sigm(go) * tanh_f(c0);
      G1[pc * 131072 + (bg * 16 + crow) * 256 + hg * 32 + cu] = (half_t)h; }
    __syncthreads();  // all G1 stores drained (vmcnt(0) before s_barrier)

    // ---- one release + one spin per step; flag[t] transitively covers h2[t-1] ----
    if (tid == 0) {
      __threadfence();
      __hip_atomic_fetch_add(&FL[t * NBG + bg], 1u, __ATOMIC_RELAXED, __HIP_MEMORY_SCOPE_AGENT);
      while (__hip_atomic_load(&FL[t * NBG + bg], __ATOMIC_RELAXED, __HIP_MEMORY_SCOPE_AGENT) < NHG) {}
      __threadfence();  // acquire: invalidate stale L1/L2 before staging reads
    }
    __syncthreads();

    // ---- stage full h1[t], h2[t-1] (fp16, 8KB each) + x_{t+1} into LDS ----
    { int u8 = (tid & 31) * 8;
      int bo = crow * 512 + u8 * 2; bo ^= (crow & 7) << 4;
      uint4 v1 = *(const uint4*)(G1 + pc * 131072 + (bg * 16 + crow) * 256 + u8);
      *(uint4*)(H1c + bo) = v1;
      if (t > 0) {
        uint4 v2 = *(const uint4*)(G2 + pm * 131072 + (bg * 16 + crow) * 256 + u8);
        *(uint4*)(H2p + bo) = v2;
      }
      if (have_x) {
        union { half_t h[2]; u32 u; } cvx;
        cvx.h[0] = (half_t)xv.x; cvx.h[1] = (half_t)xv.y;
        int bx = crow * 128 + (tid & 31) * 4; bx ^= (crow & 7) << 4;
        *(u32*)(smem + pm * 2048 + bx) = cvx.u;
      }
    }
    __syncthreads();

    // ---- layer 1: gates = [h1[t] | h2[t-1]] @ W1^T ----
    f32x4 acc2 = {0.f, 0.f, 0.f, 0.f};
    #pragma unroll
    for (int kc = 0; kc < 16; kc++) {
      const char* bsrc; int byo;
      if (kc < 8) { bsrc = H1c; byo = l15 * 512 + kc * 64 + l4 * 16; }
      else        { bsrc = H2p; byo = l15 * 512 + (kc - 8) * 64 + l4 * 16; }
      byo ^= (l15 & 7) << 4;
      f16x8 a = *(const f16x8*)(bsrc + byo);
      acc2 = __builtin_amdgcn_mfma_f32_16x16x32_f16(a, B1r[kc], acc2, 0, 0, 0);
    }
    { int g = l15 >> 2, uc = (w << 2) + (l15 & 3);
      #pragma unroll
      for (int r = 0; r < 4; r++) gbuf[g * 528 + (l4 * 4 + r) * 33 + uc] = acc2[r]; }
    __syncthreads();

    // ---- cell 1, h2 -> global slice (+ f32 copy at final step) ----
    { float gi = gbuf[0 * 528 + crow * 33 + cu] + bv1[0];
      float gf = gbuf[1 * 528 + crow * 33 + cu] + bv1[1];
      float gg = gbuf[2 * 528 + crow * 33 + cu] + bv1[2];
      float go = gbuf[3 * 528 + crow * 33 + cu] + bv1[3];
      c1 = sigm(gf) * c1 + sigm(gi) * tanh_f(gg);
      float h = sigm(go) * tanh_f(c1);
      G2[pc * 131072 + (bg * 16 + crow) * 256 + hg * 32 + cu] = (half_t)h;
      if (t == T_STEPS - 1) G2F[(bg * 16 + crow) * 256 + hg * 32 + cu] = h; }
    __syncthreads();
  }

  // final release so LN blocks can gather all partners' f32 h2
  if (tid == 0) {
    __threadfence();
    __hip_atomic_fetch_add(&FL[T_STEPS * NBG + bg], 1u, __ATOMIC_RELAXED, __HIP_MEMORY_SCOPE_AGENT);
  }
  if (hg != 0) return;

  if (tid == 0) {
    while (__hip_atomic_load(&FL[T_STEPS * NBG + bg], __ATOMIC_RELAXED, __HIP_MEMORY_SCOPE_AGENT) < NHG) {}
    __threadfence();
  }
  __syncthreads();

  // ---- LayerNorm + exact GELU + head on h2[:, -1] (f32 path) ----
  float* HF = (float*)smem;  // [16][256] f32, reuse LDS
  for (int i = tid; i < 4096; i += 512) HF[i] = G2F[bg * 4096 + i];
  __syncthreads();

  float hbv = headb[0];
  #pragma unroll
  for (int rj = 0; rj < 2; rj++) {
    int rr = w * 2 + rj;
    float v[4], s = 0.f;
    #pragma unroll
    for (int q = 0; q < 4; q++) { v[q] = HF[rr * 256 + q * 64 + lane]; s += v[q]; }
    s = wsum(s);
    float mu = s * (1.0f / 256.0f);
    float vs = 0.f;
    #pragma unroll
    for (int q = 0; q < 4; q++) { float d = v[q] - mu; vs += d * d; }
    vs = wsum(vs);
    float rstd = rsqrtf(vs * (1.0f / 256.0f) + 1e-5f);
    float dot = 0.f;
    #pragma unroll
    for (int q = 0; q < 4; q++) {
      int uu = q * 64 + lane;
      float y = (v[q] - mu) * rstd * gam[uu] + bet[uu];
      float ge = 0.5f * y * (1.0f + erff(y * 0.70710678118f));
      dot += ge * headw[uu];
    }
    dot = wsum(dot);
    if (lane == 0) out[bg * 16 + rr] = dot + hbv;
  }
}

extern "C" void kernel_launch(void* const* d_in, const int* in_sizes, int n_in,
                              void* d_out, int out_size, void* d_ws, size_t ws_size,
                              hipStream_t stream) {
  const float* x    = (const float*)d_in[0];
  const float* wih0 = (const float*)d_in[1];
  const float* whh0 = (const float*)d_in[2];
  const float* bih0 = (const float*)d_in[3];
  const float* bhh0 = (const float*)d_in[4];
  const float* wih1 = (const float*)d_in[5];
  const float* whh1 = (const float*)d_in[6];
  const float* bih1 = (const float*)d_in[7];
  const float* bhh1 = (const float*)d_in[8];
  const float* gam  = (const float*)d_in[9];
  const float* bet  = (const float*)d_in[10];
  const float* hw   = (const float*)d_in[11];
  const float* hb   = (const float*)d_in[12];
  char* ws = (char*)d_ws;  // needs ~3.31 MB

  hipLaunchKernelGGL(init_flags, dim3(17), dim3(512), 0, stream, (u32*)(ws + FL_OFF));
  hipLaunchKernelGGL(pack_weights, dim3(3328), dim3(256), 0, stream,
                     wih0, whh0, wih1, whh1, (half_t*)ws);
  hipLaunchKernelGGL(lstm_fused, dim3(256), dim3(512), 0, stream,
                     x, bih0, bhh0, bih1, bhh1, gam, bet, hw, hb, ws, (float*)d_out);
}

// Round 3
// 1409.586 us; speedup vs baseline: 11.1956x; 2.4269x over previous
//
#include <hip/hip_runtime.h>

typedef _Float16 half_t;
typedef half_t f16x8 __attribute__((ext_vector_type(8)));
typedef float  f32x4 __attribute__((ext_vector_type(4)));
typedef unsigned int u32;
typedef unsigned long long u64;
typedef unsigned short u16;

#define T_STEPS 256
#define NBG 32
#define NHG 8

// workspace: [packed fp16 weights | tagged ring]
#define WB_BYTES  1703936u
#define RING_OFF  WB_BYTES            // u64[2 slots][32 bg][8 hg][512 words] = 2 MiB
// total ws = 3,801,088 bytes

// ---------------- prep: pack fp32 weights into fp16 MFMA B-fragment order ----------------
// Layout: [hg 8][w 8][kc 26][lane 64][8 halves]; kc 0..9 layer0 (K=320), 10..25 layer1 (K=512).
// Wave (hg,w) owns 16 gate-cols: c16 -> gate g=c16>>2, unit = hg*32 + w*4 + (c16&3).
__global__ void pack_weights(const float* __restrict__ wih0, const float* __restrict__ whh0,
                             const float* __restrict__ wih1, const float* __restrict__ whh1,
                             half_t* __restrict__ wsB) {
  int idx = blockIdx.x * 256 + threadIdx.x;       // < 64*26*512 = 851968
  int j    = idx & 7;
  int lane = (idx >> 3) & 63;
  int kc   = (idx >> 9) % 26;
  int sl   = (idx >> 9) / 26;                     // hg*8 + w
  int hg = sl >> 3, w = sl & 7;
  int c16 = lane & 15;
  int g = c16 >> 2, ul = c16 & 3;
  int col = g * 256 + hg * 32 + w * 4 + ul;       // PyTorch gate order i,f,g,o
  int kf = ((lane >> 4) << 3) + j;
  float v;
  if (kc < 10) { int kk = kc * 32 + kf;        v = (kk < 64)  ? wih0[col * 64 + kk]  : whh0[col * 256 + kk - 64]; }
  else         { int kk = (kc - 10) * 32 + kf; v = (kk < 256) ? wih1[col * 256 + kk] : whh1[col * 256 + kk - 256]; }
  wsB[idx] = (half_t)v;
}

__device__ __forceinline__ float sigm(float x)   { return 1.0f / (1.0f + __expf(-x)); }
__device__ __forceinline__ float tanh_f(float x) { return 1.0f - 2.0f / (__expf(2.0f * x) + 1.0f); }
__device__ __forceinline__ float wsum(float v) {
  #pragma unroll
  for (int m = 1; m < 64; m <<= 1) v += __shfl_xor(v, m, 64);
  return v;
}

// LDS map: X0 0 (2KB) | X1 2048 | H1 4096 (8KB) | H2 12288 (8KB) | gb0 20480 (8448) | gb1 28928 (8448)
// f16 tiles XOR-swizzled: byte ^= (row&7)<<4  (G4: breaks stride-512/128 conflicts).
#define LDS_BYTES 37376

__device__ __forceinline__ f16x8 ldA(const char* base, int stride, int kc, int l15, int l4) {
  int byo = l15 * stride + kc * 64 + l4 * 16;
  byo ^= (l15 & 7) << 4;
  return *(const f16x8*)(base + byo);
}
__device__ __forceinline__ void put_acc(float* gb, const f32x4& acc, int w, int l15, int l4) {
  int g = l15 >> 2, uc = (w << 2) + (l15 & 3);
  #pragma unroll
  for (int r = 0; r < 4; r++) gb[g * 528 + (l4 * 4 + r) * 33 + uc] = acc[r];
}
__device__ __forceinline__ float cell_up(const float* gb, int crow, int cu,
                                         const float bv[4], float& c) {
  float gi = gb[0 * 528 + crow * 33 + cu] + bv[0];
  float gf = gb[1 * 528 + crow * 33 + cu] + bv[1];
  float gg = gb[2 * 528 + crow * 33 + cu] + bv[2];
  float go = gb[3 * 528 + crow * 33 + cu] + bv[3];
  c = sigm(gf) * c + sigm(gi) * tanh_f(gg);
  return sigm(go) * tanh_f(c);
}

// Poll 8 contiguous tagged words of one partner; unpack {h1,h2} halves into swizzled LDS tiles.
__device__ __forceinline__ void gather_h(const u64* slotbase, u32 want, int tid,
                                         char* H1, char* H2) {
  const int r = tid >> 5, q = tid & 31;
  const int p = q >> 2, j0 = (q & 3) * 8;
  const u64* src = slotbase + (size_t)p * 512 + r * 32 + j0;
  u64 v[8];
  for (;;) {
    bool ok = true;
    #pragma unroll
    for (int k = 0; k < 8; k++) {
      v[k] = __hip_atomic_load(&src[k], __ATOMIC_RELAXED, __HIP_MEMORY_SCOPE_AGENT);
      ok &= ((u32)v[k] == want);
    }
    if (ok) break;
    __builtin_amdgcn_s_sleep(1);
  }
  union { u16 us[8]; uint4 u4; } a1, a2;
  #pragma unroll
  for (int k = 0; k < 8; k++) {
    a1.us[k] = (u16)(v[k] >> 32);
    a2.us[k] = (u16)(v[k] >> 48);
  }
  int bo = r * 512 + (p * 32 + j0) * 2; bo ^= (r & 7) << 4;
  *(uint4*)(H1 + bo) = a1.u4;
  *(uint4*)(H2 + bo) = a2.u4;
}

// 256 blocks x 512 threads (8 waves). Block (bg,hg): 16 batch rows x 32 hidden units (4 gates).
// Weights live in registers; h exchanged via fence-free tagged device-scope atomics.
__global__ __launch_bounds__(512, 2)
void lstm_fused(const float* __restrict__ x,
                const float* __restrict__ bih0, const float* __restrict__ bhh0,
                const float* __restrict__ bih1, const float* __restrict__ bhh1,
                const float* __restrict__ gam, const float* __restrict__ bet,
                const float* __restrict__ headw, const float* __restrict__ headb,
                char* __restrict__ ws, float* __restrict__ out) {
  __shared__ __align__(16) char smem[LDS_BYTES];
  char* X0 = smem;
  char* X1 = smem + 2048;
  char* H1 = smem + 4096;
  char* H2 = smem + 12288;
  float* gb0 = (float*)(smem + 20480);
  float* gb1 = (float*)(smem + 28928);

  const int tid = threadIdx.x;
  const int w = tid >> 6, lane = tid & 63;
  const int l15 = lane & 15, l4 = lane >> 4;
  const int hg = blockIdx.x >> 5, bg = blockIdx.x & 31;
  const int crow = tid >> 5, cu = tid & 31;

  half_t* wsB = (half_t*)ws;
  u64* RING = (u64*)(ws + RING_OFF);

  // ---- weights -> registers, once ----
  f16x8 B0r[10], B1r[16];
  { const f16x8* wp = (const f16x8*)wsB + (hg * 8 + w) * 26 * 64 + lane;
    #pragma unroll
    for (int kc = 0; kc < 10; kc++) B0r[kc] = wp[kc * 64];
    #pragma unroll
    for (int kc = 0; kc < 16; kc++) B1r[kc] = wp[(10 + kc) * 64];
  }
  float bv0[4], bv1[4];
  #pragma unroll
  for (int g = 0; g < 4; g++) {
    int c = g * 256 + hg * 32 + cu;
    bv0[g] = bih0[c] + bhh0[c];
    bv1[g] = bih1[c] + bhh1[c];
  }
  float c0 = 0.f, c1 = 0.f;

  // ---- prologue: zero H1; stage x0,x1; MM0(0); cell0 -> h1[0]; publish/gather tag 0 ----
  for (int i = tid; i < 2048; i += 512) ((u32*)H1)[i] = 0;
  #pragma unroll
  for (int s = 0; s < 2; s++) {
    float2 v = *(const float2*)(x + ((size_t)(bg * 16 + crow) * T_STEPS + s) * 64 + (tid & 31) * 2);
    union { half_t h[2]; u32 u; } cv;
    cv.h[0] = (half_t)v.x; cv.h[1] = (half_t)v.y;
    int bx = crow * 128 + (tid & 31) * 4; bx ^= (crow & 7) << 4;
    *(u32*)(smem + s * 2048 + bx) = cv.u;
  }
  __syncthreads();
  {
    f32x4 a0v = {0.f, 0.f, 0.f, 0.f};
    #pragma unroll
    for (int kc = 0; kc < 10; kc++) {
      f16x8 A0 = (kc < 2) ? ldA(X0, 128, kc, l15, l4) : ldA(H1, 512, kc - 2, l15, l4);
      a0v = __builtin_amdgcn_mfma_f32_16x16x32_f16(A0, B0r[kc], a0v, 0, 0, 0);
    }
    put_acc(gb0, a0v, w, l15, l4);
    __syncthreads();
    float h1f = cell_up(gb0, crow, cu, bv0, c0);
    union { half_t h; u16 s; } ch; ch.h = (half_t)h1f;
    u64* slotbase = RING + ((size_t)0 * NBG + bg) * (NHG * 512);
    u64 word = (u64)0u | ((u64)(u32)ch.s << 32);   // tag 0, payload {h2=0, h1}
    __hip_atomic_store(&slotbase[hg * 512 + tid], word, __ATOMIC_RELAXED, __HIP_MEMORY_SCOPE_AGENT);
    asm volatile("s_waitcnt vmcnt(0)" ::: "memory");
    gather_h(slotbase, 0u, tid, H1, H2);
  }
  __syncthreads();

  // ---- main loop: iter i does MM1(i) + MM0(i+1), cells, one exchange {h1[i+1], h2[i]} ----
  for (int i = 0; i < T_STEPS - 1; i++) {
    const u32 tag = (u32)(i + 1);
    float2 xv;
    const bool have_x = (i + 2 < T_STEPS);
    if (have_x) xv = *(const float2*)(x + ((size_t)(bg * 16 + crow) * T_STEPS + (i + 2)) * 64 + (tid & 31) * 2);

    const char* Xc = smem + ((i + 1) & 1) * 2048;
    f32x4 a1v = {0.f, 0.f, 0.f, 0.f}, a0v = {0.f, 0.f, 0.f, 0.f};
    #pragma unroll
    for (int kc = 0; kc < 10; kc++) {   // interleave the two acc chains for ILP
      f16x8 A1 = (kc < 8) ? ldA(H1, 512, kc, l15, l4) : ldA(H2, 512, kc - 8, l15, l4);
      a1v = __builtin_amdgcn_mfma_f32_16x16x32_f16(A1, B1r[kc], a1v, 0, 0, 0);
      f16x8 A0 = (kc < 2) ? ldA(Xc, 128, kc, l15, l4) : ldA(H1, 512, kc - 2, l15, l4);
      a0v = __builtin_amdgcn_mfma_f32_16x16x32_f16(A0, B0r[kc], a0v, 0, 0, 0);
    }
    #pragma unroll
    for (int kc = 10; kc < 16; kc++) {
      f16x8 A1 = ldA(H2, 512, kc - 8, l15, l4);
      a1v = __builtin_amdgcn_mfma_f32_16x16x32_f16(A1, B1r[kc], a1v, 0, 0, 0);
    }
    put_acc(gb1, a1v, w, l15, l4);
    put_acc(gb0, a0v, w, l15, l4);
    __syncthreads();

    float h2f = cell_up(gb1, crow, cu, bv1, c1);   // h2[i]
    float h1f = cell_up(gb0, crow, cu, bv0, c0);   // h1[i+1]

    union { half_t h; u16 s; } ch1, ch2;
    ch1.h = (half_t)h1f; ch2.h = (half_t)h2f;
    u32 payload = (u32)ch1.s | ((u32)ch2.s << 16);
    u64 word = (u64)tag | ((u64)payload << 32);
    u64* slotbase = RING + ((size_t)(tag & 1) * NBG + bg) * (NHG * 512);
    __hip_atomic_store(&slotbase[hg * 512 + tid], word, __ATOMIC_RELAXED, __HIP_MEMORY_SCOPE_AGENT);
    asm volatile("s_waitcnt vmcnt(0)" ::: "memory");
    gather_h(slotbase, tag, tid, H1, H2);

    if (have_x) {
      union { half_t h[2]; u32 u; } cv;
      cv.h[0] = (half_t)xv.x; cv.h[1] = (half_t)xv.y;
      int bx = crow * 128 + (tid & 31) * 4; bx ^= (crow & 7) << 4;
      *(u32*)(smem + (i & 1) * 2048 + bx) = cv.u;
    }
    __syncthreads();
  }

  // ---- final: MM1(T-1), cell1 -> h2[T-1]; publish f32 (tag T) ----
  {
    f32x4 a1v = {0.f, 0.f, 0.f, 0.f};
    #pragma unroll
    for (int kc = 0; kc < 16; kc++) {
      f16x8 A1 = (kc < 8) ? ldA(H1, 512, kc, l15, l4) : ldA(H2, 512, kc - 8, l15, l4);
      a1v = __builtin_amdgcn_mfma_f32_16x16x32_f16(A1, B1r[kc], a1v, 0, 0, 0);
    }
    put_acc(gb1, a1v, w, l15, l4);
    __syncthreads();
    float h2f = cell_up(gb1, crow, cu, bv1, c1);
    u64* slotbase = RING + ((size_t)(T_STEPS & 1) * NBG + bg) * (NHG * 512);
    u64 word = (u64)(u32)T_STEPS | ((u64)__float_as_uint(h2f) << 32);
    __hip_atomic_store(&slotbase[hg * 512 + tid], word, __ATOMIC_RELAXED, __HIP_MEMORY_SCOPE_AGENT);
    asm volatile("s_waitcnt vmcnt(0)" ::: "memory");
  }
  if (hg != 0) return;

  // ---- LN blocks (hg==0): gather f32 h2[T-1] from 8 partners -> LN + GELU + head ----
  float* HF = (float*)smem;  // [16][256] f32 (X/H1/H2 regions are dead)
  {
    const int r = tid >> 5, q = tid & 31;
    const int p = q >> 2, j0 = (q & 3) * 8;
    const u64* src = RING + ((size_t)(T_STEPS & 1) * NBG + bg) * (NHG * 512) + (size_t)p * 512 + r * 32 + j0;
    u64 v[8];
    for (;;) {
      bool ok = true;
      #pragma unroll
      for (int k = 0; k < 8; k++) {
        v[k] = __hip_atomic_load(&src[k], __ATOMIC_RELAXED, __HIP_MEMORY_SCOPE_AGENT);
        ok &= ((u32)v[k] == (u32)T_STEPS);
      }
      if (ok) break;
      __builtin_amdgcn_s_sleep(1);
    }
    #pragma unroll
    for (int k = 0; k < 8; k++)
      HF[r * 256 + p * 32 + j0 + k] = __uint_as_float((u32)(v[k] >> 32));
  }
  __syncthreads();

  float hbv = headb[0];
  #pragma unroll
  for (int rj = 0; rj < 2; rj++) {
    int rr = w * 2 + rj;
    float v[4], s = 0.f;
    #pragma unroll
    for (int q = 0; q < 4; q++) { v[q] = HF[rr * 256 + q * 64 + lane]; s += v[q]; }
    s = wsum(s);
    float mu = s * (1.0f / 256.0f);
    float vs = 0.f;
    #pragma unroll
    for (int q = 0; q < 4; q++) { float d = v[q] - mu; vs += d * d; }
    vs = wsum(vs);
    float rstd = rsqrtf(vs * (1.0f / 256.0f) + 1e-5f);
    float dot = 0.f;
    #pragma unroll
    for (int q = 0; q < 4; q++) {
      int uu = q * 64 + lane;
      float y = (v[q] - mu) * rstd * gam[uu] + bet[uu];
      float ge = 0.5f * y * (1.0f + erff(y * 0.70710678118f));
      dot += ge * headw[uu];
    }
    dot = wsum(dot);
    if (lane == 0) out[bg * 16 + rr] = dot + hbv;
  }
}

extern "C" void kernel_launch(void* const* d_in, const int* in_sizes, int n_in,
                              void* d_out, int out_size, void* d_ws, size_t ws_size,
                              hipStream_t stream) {
  const float* x    = (const float*)d_in[0];
  const float* wih0 = (const float*)d_in[1];
  const float* whh0 = (const float*)d_in[2];
  const float* bih0 = (const float*)d_in[3];
  const float* bhh0 = (const float*)d_in[4];
  const float* wih1 = (const float*)d_in[5];
  const float* whh1 = (const float*)d_in[6];
  const float* bih1 = (const float*)d_in[7];
  const float* bhh1 = (const float*)d_in[8];
  const float* gam  = (const float*)d_in[9];
  const float* bet  = (const float*)d_in[10];
  const float* hw   = (const float*)d_in[11];
  const float* hb   = (const float*)d_in[12];
  char* ws = (char*)d_ws;  // needs 3,801,088 bytes

  hipLaunchKernelGGL(pack_weights, dim3(3328), dim3(256), 0, stream,
                     wih0, whh0, wih1, whh1, (half_t*)ws);
  hipLaunchKernelGGL(lstm_fused, dim3(256), dim3(512), 0, stream,
                     x, bih0, bhh0, bih1, bhh1, gam, bet, hw, hb, ws, (float*)d_out);
}